// Round 6
// baseline (430.722 us; speedup 1.0000x reference)
//
#include <hip/hip_runtime.h>
#include <stdint.h>
#include <math.h>

// ReformerAttention on MI355X — all fp32 I/O (per reference dtypes).
// B=2, T=2048, E=512, H=8, Dh=64, 2 hash rounds, buckets<32 attend.
// Projection row p (of the [T*B,E]-flattened swapaxes result) = logical
// (b'=p/T, t'=p%T); it gathers input row (b=p%2, t=p/2).
//
// Pipeline: qkv_gemm(128²) -> hash -> memset(cnt,attn) -> hist(k,q) -> scan
//           -> scatter(k,q) -> attn_bucket (dense per-bucket tiles, atomicAdd)
//           -> out_gemm(128²)

#define T_ 2048
#define E_ 512
#define H_ 8
#define DH_ 64
#define B_ 2
#define M_ 4096        // B_*T_
#define NROUND 2
#define NBUCKET 32
#define NSEG 32        // NROUND * 16 (r,ctx) segments

// ---------------------------------------------------------------------------
// QKV projection, 128x128 tile, 8x8 microtile (4+4 split halves).
// C[p,n] = sum_k X[gather(p),k]*W[n,k] + bias[n]
// ---------------------------------------------------------------------------
__global__ __launch_bounds__(256) void qkv_gemm(
    const float* __restrict__ Xq, const float* __restrict__ Xk,
    const float* __restrict__ Xv,
    const float* __restrict__ Wq, const float* __restrict__ bq,
    const float* __restrict__ Wk, const float* __restrict__ bk,
    const float* __restrict__ Wv, const float* __restrict__ bv,
    float* __restrict__ Qo, float* __restrict__ Ko, float* __restrict__ Vo)
{
  const float* X; const float* W; const float* bias; float* C;
  if (blockIdx.z == 0)      { X = Xq; W = Wq; bias = bq; C = Qo; }
  else if (blockIdx.z == 1) { X = Xk; W = Wk; bias = bk; C = Ko; }
  else                      { X = Xv; W = Wv; bias = bv; C = Vo; }

  __shared__ __align__(16) float As[16 * 132];  // [k][m], pad 132
  __shared__ __align__(16) float Bs[16 * 132];  // [k][n]

  const int tid = threadIdx.x;
  const int tx = tid & 15, ty = tid >> 4;
  const int m0 = blockIdx.y * 128, n0 = blockIdx.x * 128;

  float acc[8][8] = {};

  for (int k0 = 0; k0 < E_; k0 += 16) {
    float4 ag[2], bg[2];
#pragma unroll
    for (int it = 0; it < 2; it++) {
      const int fidx = it * 256 + tid;       // 0..511
      const int row = fidx >> 2, k4 = fidx & 3;
      const int am = m0 + row;
      const long arow = (long)(am & 1) * T_ + (am >> 1);   // batch/time gather
      ag[it] = *(const float4*)(X + arow * E_ + k0 + k4 * 4);
      bg[it] = *(const float4*)(W + (long)(n0 + row) * E_ + k0 + k4 * 4);
    }
    __syncthreads();
#pragma unroll
    for (int it = 0; it < 2; it++) {
      const int fidx = it * 256 + tid;
      const int row = fidx >> 2, k4 = fidx & 3;
      As[(k4 * 4 + 0) * 132 + row] = ag[it].x;
      As[(k4 * 4 + 1) * 132 + row] = ag[it].y;
      As[(k4 * 4 + 2) * 132 + row] = ag[it].z;
      As[(k4 * 4 + 3) * 132 + row] = ag[it].w;
      Bs[(k4 * 4 + 0) * 132 + row] = bg[it].x;
      Bs[(k4 * 4 + 1) * 132 + row] = bg[it].y;
      Bs[(k4 * 4 + 2) * 132 + row] = bg[it].z;
      Bs[(k4 * 4 + 3) * 132 + row] = bg[it].w;
    }
    __syncthreads();
#pragma unroll
    for (int kk = 0; kk < 16; kk++) {
      const float4 a0 = *(const float4*)&As[kk * 132 + ty * 4];
      const float4 a1 = *(const float4*)&As[kk * 132 + 64 + ty * 4];
      const float4 b0 = *(const float4*)&Bs[kk * 132 + tx * 4];
      const float4 b1 = *(const float4*)&Bs[kk * 132 + 64 + tx * 4];
      const float av[8] = {a0.x,a0.y,a0.z,a0.w, a1.x,a1.y,a1.z,a1.w};
      const float bv2[8] = {b0.x,b0.y,b0.z,b0.w, b1.x,b1.y,b1.z,b1.w};
#pragma unroll
      for (int i = 0; i < 8; i++)
#pragma unroll
        for (int j = 0; j < 8; j++) acc[i][j] += av[i] * bv2[j];
    }
  }

#pragma unroll
  for (int i = 0; i < 8; i++) {
    const int mm = m0 + ((i < 4) ? (ty * 4 + i) : (64 + ty * 4 + i - 4));
#pragma unroll
    for (int jh = 0; jh < 2; jh++) {
      const int nn = n0 + jh * 64 + tx * 4;
      float4 o;
      o.x = acc[i][jh * 4 + 0] + bias[nn + 0];
      o.y = acc[i][jh * 4 + 1] + bias[nn + 1];
      o.z = acc[i][jh * 4 + 2] + bias[nn + 2];
      o.w = acc[i][jh * 4 + 3] + bias[nn + 3];
      *(float4*)(C + (long)mm * E_ + nn) = o;
    }
  }
}

// ---------------------------------------------------------------------------
// Output projection, 128x128 tile: out[perm(p), n] = sum_k A[p,k]*W[n,k]+b[n]
// perm(p) = (p%T)*2 + p/T.
// ---------------------------------------------------------------------------
__global__ __launch_bounds__(256) void out_gemm(
    const float* __restrict__ A, const float* __restrict__ W,
    const float* __restrict__ bias, float* __restrict__ C)
{
  __shared__ __align__(16) float As[16 * 132];
  __shared__ __align__(16) float Bs[16 * 132];

  const int tid = threadIdx.x;
  const int tx = tid & 15, ty = tid >> 4;
  const int m0 = blockIdx.y * 128, n0 = blockIdx.x * 128;

  float acc[8][8] = {};

  for (int k0 = 0; k0 < E_; k0 += 16) {
    float4 ag[2], bg[2];
#pragma unroll
    for (int it = 0; it < 2; it++) {
      const int fidx = it * 256 + tid;
      const int row = fidx >> 2, k4 = fidx & 3;
      ag[it] = *(const float4*)(A + (long)(m0 + row) * E_ + k0 + k4 * 4);
      bg[it] = *(const float4*)(W + (long)(n0 + row) * E_ + k0 + k4 * 4);
    }
    __syncthreads();
#pragma unroll
    for (int it = 0; it < 2; it++) {
      const int fidx = it * 256 + tid;
      const int row = fidx >> 2, k4 = fidx & 3;
      As[(k4 * 4 + 0) * 132 + row] = ag[it].x;
      As[(k4 * 4 + 1) * 132 + row] = ag[it].y;
      As[(k4 * 4 + 2) * 132 + row] = ag[it].z;
      As[(k4 * 4 + 3) * 132 + row] = ag[it].w;
      Bs[(k4 * 4 + 0) * 132 + row] = bg[it].x;
      Bs[(k4 * 4 + 1) * 132 + row] = bg[it].y;
      Bs[(k4 * 4 + 2) * 132 + row] = bg[it].z;
      Bs[(k4 * 4 + 3) * 132 + row] = bg[it].w;
    }
    __syncthreads();
#pragma unroll
    for (int kk = 0; kk < 16; kk++) {
      const float4 a0 = *(const float4*)&As[kk * 132 + ty * 4];
      const float4 a1 = *(const float4*)&As[kk * 132 + 64 + ty * 4];
      const float4 b0 = *(const float4*)&Bs[kk * 132 + tx * 4];
      const float4 b1 = *(const float4*)&Bs[kk * 132 + 64 + tx * 4];
      const float av[8] = {a0.x,a0.y,a0.z,a0.w, a1.x,a1.y,a1.z,a1.w};
      const float bv2[8] = {b0.x,b0.y,b0.z,b0.w, b1.x,b1.y,b1.z,b1.w};
#pragma unroll
      for (int i = 0; i < 8; i++)
#pragma unroll
        for (int j = 0; j < 8; j++) acc[i][j] += av[i] * bv2[j];
    }
  }

#pragma unroll
  for (int i = 0; i < 8; i++) {
    const int mm = m0 + ((i < 4) ? (ty * 4 + i) : (64 + ty * 4 + i - 4));
    const int crow = (mm & (T_ - 1)) * B_ + (mm >> 11);   // t'*2 + b'
#pragma unroll
    for (int jh = 0; jh < 2; jh++) {
      const int nn = n0 + jh * 64 + tx * 4;
      float4 o;
      o.x = acc[i][jh * 4 + 0] + bias[nn + 0];
      o.y = acc[i][jh * 4 + 1] + bias[nn + 1];
      o.z = acc[i][jh * 4 + 2] + bias[nn + 2];
      o.w = acc[i][jh * 4 + 3] + bias[nn + 3];
      *(float4*)(C + (long)crow * E_ + nn) = o;
    }
  }
}

// ---------------------------------------------------------------------------
// LSH hash, thread-per-row (unchanged — ~15 µs).
// ---------------------------------------------------------------------------
__global__ __launch_bounds__(128) void hash_kernel(
    const float* __restrict__ Q, const float* __restrict__ K,
    const float* __restrict__ lshW, const float* __restrict__ lshb,
    int* __restrict__ qh, int* __restrict__ kh)
{
  __shared__ __align__(16) float xs[128 * 68];
  const int tid = threadIdx.x;
  const int tau0 = blockIdx.x * 128;
  const int src = tau0 >> 16;          // uniform per block
  const int r = (tau0 >> 15) & 1;
  const int rowbase = tau0 & 32767;
  const float* X = src ? K : Q;
  int* outh = src ? kh : qh;

  const float4* g = (const float4*)(X + (long)rowbase * 64);
#pragma unroll
  for (int it = 0; it < 16; it++) {
    const int gidx = it * 128 + tid;
    const int row = gidx >> 4, c4 = gidx & 15;
    *(float4*)&xs[row * 68 + c4 * 4] = g[gidx];
  }
  __syncthreads();

  float4 x[16];
#pragma unroll
  for (int i = 0; i < 16; i++) x[i] = *(const float4*)&xs[tid * 68 + i * 4];

  const float4* w4 = (const float4*)(lshW + (long)r * DH_ * DH_);
  const float* bb = lshb + r * DH_;

  float best = -INFINITY; int bi = 0;
  for (int j = 0; j < 64; j++) {
    float s = bb[j];
#pragma unroll
    for (int d = 0; d < 16; d++) {
      const float4 w = w4[j * 16 + d];       // wave-uniform -> s_load
      s += x[d].x * w.x + x[d].y * w.y + x[d].z * w.z + x[d].w * w.w;
    }
    if (s > best) { best = s; bi = j; }
  }

  const int rowidx = rowbase + tid;
  const int p = rowidx >> 3, h = rowidx & 7;
  const int b = p >> 11, t = p & (T_ - 1);
  outh[((r * 16) + b * H_ + h) * T_ + t] = bi;
}

// ---------------------------------------------------------------------------
// Bucket sort (applied to both kh and qh): histogram -> scan -> scatter.
// seg = idx>>11 (32 segments of 2048). Only values<32 are attendable.
// ---------------------------------------------------------------------------
__global__ __launch_bounds__(256) void hist_kernel(
    const int* __restrict__ hsh, int* __restrict__ cnt)
{
  const int idx = blockIdx.x * 256 + threadIdx.x;
  const int v = hsh[idx];
  if (v < NBUCKET) atomicAdd(&cnt[(idx >> 11) * NBUCKET + v], 1);
}

__global__ void scan_kernel(const int* __restrict__ kcnt, int* __restrict__ koff,
                            int* __restrict__ kcur,
                            const int* __restrict__ qcnt, int* __restrict__ qoff,
                            int* __restrict__ qcur)
{
  const int t = threadIdx.x;
  const int seg = t & 31;
  const int* cnt = (t < 32) ? kcnt : qcnt;
  int* off = (t < 32) ? koff : qoff;
  int* cur = (t < 32) ? kcur : qcur;
  int run = 0;
  for (int b = 0; b < NBUCKET; b++) {
    off[seg * (NBUCKET + 1) + b] = run;
    cur[seg * NBUCKET + b] = run;
    run += cnt[seg * NBUCKET + b];
  }
  off[seg * (NBUCKET + 1) + NBUCKET] = run;
}

__global__ __launch_bounds__(256) void scatter_kernel(
    const int* __restrict__ hsh, int* __restrict__ cur, int* __restrict__ list)
{
  const int idx = blockIdx.x * 256 + threadIdx.x;
  const int v = hsh[idx];
  if (v < NBUCKET) {
    const int seg = idx >> 11;
    const int pos = atomicAdd(&cur[seg * NBUCKET + v], 1);
    list[seg * T_ + pos] = idx & (T_ - 1);
  }
}

// ---------------------------------------------------------------------------
// Dense per-bucket attention. One block per (seg,bucket): nq×nk tiny
// attention (avg 32×32), Q/K/V tiles in LDS. Thread (qrow,col): computes
// S[qrow][k] for k=kk*8+col (serial LDS dots — no shuffles), P=exp, then
// accumulates 8 dims of O + l over all keys. No-max softmax (scores bounded).
// Rounds accumulate into attn via fp32 atomicAdd (addresses touched <=2x).
// ---------------------------------------------------------------------------
__global__ __launch_bounds__(256) void attn_bucket(
    const float* __restrict__ Q, const float* __restrict__ K,
    const float* __restrict__ V,
    const int* __restrict__ qlist, const int* __restrict__ qoff,
    const int* __restrict__ klist, const int* __restrict__ koff,
    float* __restrict__ attn)   // [M_*E_], pre-zeroed
{
  __shared__ __align__(16) float Qs[32 * 68];
  __shared__ __align__(16) float Ks[64 * 68];
  __shared__ __align__(16) float Vs[64 * 68];
  __shared__ float Ps[32 * 68];

  const int task = blockIdx.x;          // seg*32 + bucket
  const int seg = task >> 5, bucket = task & 31;
  const int ctx = seg & 15;
  const int b = ctx >> 3, h = ctx & 7;
  const int qlo = qoff[seg * (NBUCKET + 1) + bucket];
  const int nq  = qoff[seg * (NBUCKET + 1) + bucket + 1] - qlo;
  const int klo = koff[seg * (NBUCKET + 1) + bucket];
  const int nk  = koff[seg * (NBUCKET + 1) + bucket + 1] - klo;
  if (nq == 0 || nk == 0) return;       // no queries, or mask.any()==false

  const int tid = threadIdx.x;
  const int col = tid & 7, qrow = tid >> 3;     // 32 rows × 8 cols
  const float* Qb = Q + ((long)b * T_) * E_ + h * DH_;
  const float* Kb = K + ((long)b * T_) * E_ + h * DH_;
  const float* Vb = V + ((long)b * T_) * E_ + h * DH_;
  const int* ql = qlist + seg * T_;
  const int* kl = klist + seg * T_;

  for (int qt = 0; qt < nq; qt += 32) {
    const int nqt = min(32, nq - qt);
    __syncthreads();                     // protect Qs/Ks/Vs reuse
    // stage Q tile (32 rows × 16 float4), zero-fill invalid rows
#pragma unroll
    for (int it = 0; it < 2; it++) {
      const int fidx = it * 256 + tid;
      const int row = fidx >> 4, c4 = fidx & 15;
      float4 v = make_float4(0.f, 0.f, 0.f, 0.f);
      if (row < nqt) v = *(const float4*)(Qb + (long)ql[qlo + qt + row] * E_ + c4 * 4);
      *(float4*)&Qs[row * 68 + c4 * 4] = v;
    }

    float l = 0.f;
    float o[8] = {};
    for (int kt = 0; kt < nk; kt += 64) {
      const int nkt = min(64, nk - kt);
      __syncthreads();                   // prior PV reads of Vs done
#pragma unroll
      for (int it = 0; it < 4; it++) {
        const int fidx = it * 256 + tid;
        const int row = fidx >> 4, c4 = fidx & 15;
        if (row < nkt) {
          const long src = (long)kl[klo + kt + row] * E_ + c4 * 4;
          *(float4*)&Ks[row * 68 + c4 * 4] = *(const float4*)(Kb + src);
          *(float4*)&Vs[row * 68 + c4 * 4] = *(const float4*)(Vb + src);
        }
      }
      __syncthreads();
      // S phase: k = kk*8 + col (consecutive rows per instr -> conflict-free)
#pragma unroll
      for (int kk = 0; kk < 8; kk++) {
        const int k = kk * 8 + col;
        float p;
        if (k < nkt) {
          const float* qp = &Qs[qrow * 68];
          const float* kp = &Ks[k * 68];
          float s = 0.f;
#pragma unroll
          for (int d4 = 0; d4 < 16; d4++) {
            const float4 a = *(const float4*)(qp + d4 * 4);
            const float4 c = *(const float4*)(kp + d4 * 4);
            s += a.x * c.x + a.y * c.y + a.z * c.z + a.w * c.w;
          }
          p = __expf(s * 0.125f);        // 1/sqrt(64)
        } else {
          p = 0.f;
        }
        Ps[qrow * 68 + k] = p;           // row owned by this wave: no barrier
      }
      // PV phase: every thread reads full P row (l comes free)
      for (int k = 0; k < nkt; k++) {
        const float pk = Ps[qrow * 68 + k];
        l += pk;
        const float4 v0 = *(const float4*)&Vs[k * 68 + col * 8];
        const float4 v1 = *(const float4*)&Vs[k * 68 + col * 8 + 4];
        o[0] += pk * v0.x; o[1] += pk * v0.y; o[2] += pk * v0.z; o[3] += pk * v0.w;
        o[4] += pk * v1.x; o[5] += pk * v1.y; o[6] += pk * v1.z; o[7] += pk * v1.w;
      }
    }

    if (qrow < nqt) {
      const float inv = 0.5f / l;        // l >= nk*e^min > 0
      const int t = ql[qlo + qt + qrow];
      float* op = attn + ((long)b * T_ + t) * E_ + h * DH_ + col * 8;
#pragma unroll
      for (int dd = 0; dd < 8; dd++) atomicAdd(op + dd, o[dd] * inv);
    }
  }
}

// ---------------------------------------------------------------------------
extern "C" void kernel_launch(void* const* d_in, const int* in_sizes, int n_in,
                              void* d_out, int out_size, void* d_ws, size_t ws_size,
                              hipStream_t stream) {
  const float* query = (const float*)d_in[0];
  const float* key   = (const float*)d_in[1];
  const float* value = (const float*)d_in[2];
  const float* Wq = (const float*)d_in[3];
  const float* bq = (const float*)d_in[4];
  const float* Wk = (const float*)d_in[5];
  const float* bk = (const float*)d_in[6];
  const float* Wv = (const float*)d_in[7];
  const float* bv = (const float*)d_in[8];
  const float* Wo = (const float*)d_in[9];
  const float* bo = (const float*)d_in[10];
  const float* lshW = (const float*)d_in[11];
  const float* lshb = (const float*)d_in[12];

  const size_t MSZ = (size_t)M_ * E_;
  float* Q    = (float*)d_ws;            //  8 MB
  float* K    = Q + MSZ;                 //  8 MB
  float* V    = K + MSZ;                 //  8 MB
  float* attn = V + MSZ;                 //  8 MB (atomic round-accumulated)
  int* qh    = (int*)(attn + MSZ);       // [NSEG][T_]  256 KB
  int* kh    = qh + NSEG * T_;           // 256 KB
  int* klist = kh + NSEG * T_;           // 256 KB
  int* qlist = klist + NSEG * T_;        // 256 KB
  int* kcnt  = qlist + NSEG * T_;        // [NSEG][32]
  int* qcnt  = kcnt + NSEG * NBUCKET;    // [NSEG][32]  (contiguous w/ kcnt)
  int* kcur  = qcnt + NSEG * NBUCKET;
  int* qcur  = kcur + NSEG * NBUCKET;
  int* koff  = qcur + NSEG * NBUCKET;    // [NSEG][33]
  int* qoff  = koff + NSEG * (NBUCKET + 1);

  qkv_gemm<<<dim3(E_ / 128, M_ / 128, 3), 256, 0, stream>>>(
      query, key, value, Wq, bq, Wk, bk, Wv, bv, Q, K, V);
  hash_kernel<<<dim3(1024), 128, 0, stream>>>(
      Q, K, lshW, lshb, qh, kh);
  hipMemsetAsync(kcnt, 0, 2 * NSEG * NBUCKET * sizeof(int), stream);  // kcnt+qcnt
  hipMemsetAsync(attn, 0, MSZ * sizeof(float), stream);
  hist_kernel<<<dim3(NSEG * T_ / 256), 256, 0, stream>>>(kh, kcnt);
  hist_kernel<<<dim3(NSEG * T_ / 256), 256, 0, stream>>>(qh, qcnt);
  scan_kernel<<<dim3(1), 64, 0, stream>>>(kcnt, koff, kcur, qcnt, qoff, qcur);
  scatter_kernel<<<dim3(NSEG * T_ / 256), 256, 0, stream>>>(kh, kcur, klist);
  scatter_kernel<<<dim3(NSEG * T_ / 256), 256, 0, stream>>>(qh, qcur, qlist);
  attn_bucket<<<dim3(NSEG * NBUCKET), 256, 0, stream>>>(
      Q, K, V, qlist, qoff, klist, koff, attn);
  out_gemm<<<dim3(E_ / 128, M_ / 128, 1), 256, 0, stream>>>(
      attn, Wo, bo, (float*)d_out);
}

// Round 8
// 372.022 us; speedup vs baseline: 1.1578x; 1.1578x over previous
//
#include <hip/hip_runtime.h>
#include <stdint.h>
#include <math.h>

// ReformerAttention on MI355X — all fp32 I/O (per reference dtypes).
// B=2, T=2048, E=512, H=8, Dh=64, 2 hash rounds, buckets<32 attend.
// Projection row p = logical (b'=p/T, t'=p%T); gathers input row (b=p%2, t=p/2).
//
// Pipeline: qkv_gemm(64²) -> hash -> memset(cnt/ntasks, attn) -> hist(k,q)
//           -> scan(+task enumeration) -> scatter(k,q)
//           -> attn_task (16-query tasks, register-Q, unrolled PV, atomicAdd)
//           -> out_gemm(64²)

#define T_ 2048
#define E_ 512
#define H_ 8
#define DH_ 64
#define B_ 2
#define M_ 4096        // B_*T_
#define NROUND 2
#define NBUCKET 32
#define NSEG 32        // NROUND * 16 (r,ctx) segments
#define MAXTASK 5120   // 32 segs * (2048/16 + 32) upper bound

// ---------------------------------------------------------------------------
// QKV projection (64x64 tile, round-5 proven version).
// C[p,n] = sum_k X[gather(p),k]*W[n,k] + bias[n]
// ---------------------------------------------------------------------------
__global__ __launch_bounds__(256) void qkv_gemm(
    const float* __restrict__ Xq, const float* __restrict__ Xk,
    const float* __restrict__ Xv,
    const float* __restrict__ Wq, const float* __restrict__ bq,
    const float* __restrict__ Wk, const float* __restrict__ bk,
    const float* __restrict__ Wv, const float* __restrict__ bv,
    float* __restrict__ Qo, float* __restrict__ Ko, float* __restrict__ Vo)
{
  const float* X; const float* W; const float* bias; float* C;
  if (blockIdx.z == 0)      { X = Xq; W = Wq; bias = bq; C = Qo; }
  else if (blockIdx.z == 1) { X = Xk; W = Wk; bias = bk; C = Ko; }
  else                      { X = Xv; W = Wv; bias = bv; C = Vo; }

  __shared__ __align__(16) float As[16 * 68];
  __shared__ __align__(16) float Bs[16 * 68];

  const int tid = threadIdx.x;
  const int tx = tid & 15, ty = tid >> 4;
  const int m0 = blockIdx.y * 64, n0 = blockIdx.x * 64;
  const int lrow = tid >> 2;
  const int lk = (tid & 3) * 4;
  const int am = m0 + lrow;
  const long abase = ((long)(am & 1) * T_ + (am >> 1)) * E_ + lk;
  const long bbase = (long)(n0 + lrow) * E_ + lk;

  float acc[4][4] = {};

  for (int k0 = 0; k0 < E_; k0 += 16) {
    const float4 av4 = *(const float4*)(X + abase + k0);
    const float4 bv4 = *(const float4*)(W + bbase + k0);
    __syncthreads();
    As[(lk + 0) * 68 + lrow] = av4.x;
    As[(lk + 1) * 68 + lrow] = av4.y;
    As[(lk + 2) * 68 + lrow] = av4.z;
    As[(lk + 3) * 68 + lrow] = av4.w;
    Bs[(lk + 0) * 68 + lrow] = bv4.x;
    Bs[(lk + 1) * 68 + lrow] = bv4.y;
    Bs[(lk + 2) * 68 + lrow] = bv4.z;
    Bs[(lk + 3) * 68 + lrow] = bv4.w;
    __syncthreads();
#pragma unroll
    for (int kk = 0; kk < 16; kk++) {
      const float4 a = *(const float4*)&As[kk * 68 + ty * 4];
      const float4 b = *(const float4*)&Bs[kk * 68 + tx * 4];
      const float avr[4] = {a.x, a.y, a.z, a.w};
      const float bvr[4] = {b.x, b.y, b.z, b.w};
#pragma unroll
      for (int i = 0; i < 4; i++)
#pragma unroll
        for (int j = 0; j < 4; j++) acc[i][j] += avr[i] * bvr[j];
    }
  }

#pragma unroll
  for (int i = 0; i < 4; i++) {
    const int mm = m0 + ty * 4 + i;
    float4 o;
    o.x = acc[i][0] + bias[n0 + tx * 4 + 0];
    o.y = acc[i][1] + bias[n0 + tx * 4 + 1];
    o.z = acc[i][2] + bias[n0 + tx * 4 + 2];
    o.w = acc[i][3] + bias[n0 + tx * 4 + 3];
    *(float4*)(C + (long)mm * E_ + n0 + tx * 4) = o;
  }
}

// ---------------------------------------------------------------------------
// Output projection (64x64 tile): out[perm(p), n] = sum_k A[p,k]*W[n,k]+b[n]
// perm(p) = (p%T)*2 + p/T.
// ---------------------------------------------------------------------------
__global__ __launch_bounds__(256) void out_gemm(
    const float* __restrict__ A, const float* __restrict__ W,
    const float* __restrict__ bias, float* __restrict__ C)
{
  __shared__ __align__(16) float As[16 * 68];
  __shared__ __align__(16) float Bs[16 * 68];

  const int tid = threadIdx.x;
  const int tx = tid & 15, ty = tid >> 4;
  const int m0 = blockIdx.y * 64, n0 = blockIdx.x * 64;
  const int lrow = tid >> 2;
  const int lk = (tid & 3) * 4;
  const long abase = (long)(m0 + lrow) * E_ + lk;
  const long bbase = (long)(n0 + lrow) * E_ + lk;

  float acc[4][4] = {};

  for (int k0 = 0; k0 < E_; k0 += 16) {
    const float4 av4 = *(const float4*)(A + abase + k0);
    const float4 bv4 = *(const float4*)(W + bbase + k0);
    __syncthreads();
    As[(lk + 0) * 68 + lrow] = av4.x;
    As[(lk + 1) * 68 + lrow] = av4.y;
    As[(lk + 2) * 68 + lrow] = av4.z;
    As[(lk + 3) * 68 + lrow] = av4.w;
    Bs[(lk + 0) * 68 + lrow] = bv4.x;
    Bs[(lk + 1) * 68 + lrow] = bv4.y;
    Bs[(lk + 2) * 68 + lrow] = bv4.z;
    Bs[(lk + 3) * 68 + lrow] = bv4.w;
    __syncthreads();
#pragma unroll
    for (int kk = 0; kk < 16; kk++) {
      const float4 a = *(const float4*)&As[kk * 68 + ty * 4];
      const float4 b = *(const float4*)&Bs[kk * 68 + tx * 4];
      const float avr[4] = {a.x, a.y, a.z, a.w};
      const float bvr[4] = {b.x, b.y, b.z, b.w};
#pragma unroll
      for (int i = 0; i < 4; i++)
#pragma unroll
        for (int j = 0; j < 4; j++) acc[i][j] += avr[i] * bvr[j];
    }
  }

#pragma unroll
  for (int i = 0; i < 4; i++) {
    const int mm = m0 + ty * 4 + i;
    const int crow = (mm & (T_ - 1)) * B_ + (mm >> 11);  // t'*2 + b'
    float4 o;
    o.x = acc[i][0] + bias[n0 + tx * 4 + 0];
    o.y = acc[i][1] + bias[n0 + tx * 4 + 1];
    o.z = acc[i][2] + bias[n0 + tx * 4 + 2];
    o.w = acc[i][3] + bias[n0 + tx * 4 + 3];
    *(float4*)(C + (long)crow * E_ + n0 + tx * 4) = o;
  }
}

// ---------------------------------------------------------------------------
// LSH hash, thread-per-row (unchanged).
// ---------------------------------------------------------------------------
__global__ __launch_bounds__(128) void hash_kernel(
    const float* __restrict__ Q, const float* __restrict__ K,
    const float* __restrict__ lshW, const float* __restrict__ lshb,
    int* __restrict__ qh, int* __restrict__ kh)
{
  __shared__ __align__(16) float xs[128 * 68];
  const int tid = threadIdx.x;
  const int tau0 = blockIdx.x * 128;
  const int src = tau0 >> 16;
  const int r = (tau0 >> 15) & 1;
  const int rowbase = tau0 & 32767;
  const float* X = src ? K : Q;
  int* outh = src ? kh : qh;

  const float4* g = (const float4*)(X + (long)rowbase * 64);
#pragma unroll
  for (int it = 0; it < 16; it++) {
    const int gidx = it * 128 + tid;
    const int row = gidx >> 4, c4 = gidx & 15;
    *(float4*)&xs[row * 68 + c4 * 4] = g[gidx];
  }
  __syncthreads();

  float4 x[16];
#pragma unroll
  for (int i = 0; i < 16; i++) x[i] = *(const float4*)&xs[tid * 68 + i * 4];

  const float4* w4 = (const float4*)(lshW + (long)r * DH_ * DH_);
  const float* bb = lshb + r * DH_;

  float best = -INFINITY; int bi = 0;
  for (int j = 0; j < 64; j++) {
    float s = bb[j];
#pragma unroll
    for (int d = 0; d < 16; d++) {
      const float4 w = w4[j * 16 + d];
      s += x[d].x * w.x + x[d].y * w.y + x[d].z * w.z + x[d].w * w.w;
    }
    if (s > best) { best = s; bi = j; }
  }

  const int rowidx = rowbase + tid;
  const int p = rowidx >> 3, h = rowidx & 7;
  const int b = p >> 11, t = p & (T_ - 1);
  outh[((r * 16) + b * H_ + h) * T_ + t] = bi;
}

// ---------------------------------------------------------------------------
// Bucket sort (kh and qh): histogram -> scan(+task emission) -> scatter.
// ---------------------------------------------------------------------------
__global__ __launch_bounds__(256) void hist_kernel(
    const int* __restrict__ hsh, int* __restrict__ cnt)
{
  const int idx = blockIdx.x * 256 + threadIdx.x;
  const int v = hsh[idx];
  if (v < NBUCKET) atomicAdd(&cnt[(idx >> 11) * NBUCKET + v], 1);
}

__global__ void scan_kernel(const int* __restrict__ kcnt, int* __restrict__ koff,
                            int* __restrict__ kcur,
                            const int* __restrict__ qcnt, int* __restrict__ qoff,
                            int* __restrict__ qcur,
                            int* __restrict__ ntasks, int* __restrict__ tasks)
{
  const int t = threadIdx.x;
  const int seg = t & 31;
  const int* cnt = (t < 32) ? kcnt : qcnt;
  int* off = (t < 32) ? koff : qoff;
  int* cur = (t < 32) ? kcur : qcur;
  int run = 0;
  for (int b = 0; b < NBUCKET; b++) {
    off[seg * (NBUCKET + 1) + b] = run;
    cur[seg * NBUCKET + b] = run;
    run += cnt[seg * NBUCKET + b];
  }
  off[seg * (NBUCKET + 1) + NBUCKET] = run;

  if (t >= 32) {   // q side: emit 16-query tasks per non-empty bucket
    for (int b = 0; b < NBUCKET; b++) {
      const int nq = cnt[seg * NBUCKET + b];
      if (nq > 0) {
        const int nt = (nq + 15) >> 4;
        const int base = atomicAdd(ntasks, nt);
        for (int i = 0; i < nt; i++)
          tasks[base + i] = (seg << 16) | (b << 8) | i;
      }
    }
  }
}

__global__ __launch_bounds__(256) void scatter_kernel(
    const int* __restrict__ hsh, int* __restrict__ cur, int* __restrict__ list)
{
  const int idx = blockIdx.x * 256 + threadIdx.x;
  const int v = hsh[idx];
  if (v < NBUCKET) {
    const int seg = idx >> 11;
    const int pos = atomicAdd(&cur[seg * NBUCKET + v], 1);
    list[seg * T_ + pos] = idx & (T_ - 1);
  }
}

// ---------------------------------------------------------------------------
// Task-parallel dense bucket attention. One block per task = (seg, bucket,
// 16-query chunk); 256 threads = 16 qrows x 16 cols (4 dims each).
// Q rows held in REGISTERS (no LDS re-reads in S phase). K-tiles of 64 keys:
// V zero-filled beyond nkt so PV runs unrolled x4 without guards (pipelined
// independent LDS loads instead of latency-serial iterations).
// No-max softmax (bounded scores). Round results accumulated via atomicAdd.
// ---------------------------------------------------------------------------
__global__ __launch_bounds__(256) void attn_task(
    const float* __restrict__ Q, const float* __restrict__ K,
    const float* __restrict__ V,
    const int* __restrict__ qlist, const int* __restrict__ qoff,
    const int* __restrict__ klist, const int* __restrict__ koff,
    const int* __restrict__ tasks, const int* __restrict__ ntasks,
    float* __restrict__ attn)   // [M_*E_], pre-zeroed
{
  __shared__ __align__(16) float QPs[16 * 68];   // Q staging, then P
  __shared__ __align__(16) float Ks[64 * 68];
  __shared__ __align__(16) float Vs[64 * 68];

  if ((int)blockIdx.x >= *ntasks) return;
  const int tk = tasks[blockIdx.x];
  const int seg = tk >> 16, bucket = (tk >> 8) & 255, qt = tk & 255;
  const int ctx = seg & 15;
  const int b = ctx >> 3, h = ctx & 7;

  const int qlo = qoff[seg * (NBUCKET + 1) + bucket] + qt * 16;
  const int nqt = min(16, qoff[seg * (NBUCKET + 1) + bucket + 1] - qlo);
  const int klo = koff[seg * (NBUCKET + 1) + bucket];
  const int nk  = koff[seg * (NBUCKET + 1) + bucket + 1] - klo;
  if (nk == 0) return;                    // mask.any()==false -> stays zero

  const int tid = threadIdx.x;
  const int qrow = tid >> 4, col = tid & 15;
  const float* Qb = Q + ((long)b * T_) * E_ + h * DH_;
  const float* Kb = K + ((long)b * T_) * E_ + h * DH_;
  const float* Vb = V + ((long)b * T_) * E_ + h * DH_;
  const int* ql = qlist + seg * T_;
  const int* kl = klist + seg * T_;

  {  // stage Q tile: 16 rows x 16 float4, zero-fill invalid rows
    float4 v = make_float4(0.f, 0.f, 0.f, 0.f);
    if (qrow < nqt) v = *(const float4*)(Qb + (long)ql[qlo + qrow] * E_ + col * 4);
    *(float4*)&QPs[qrow * 68 + col * 4] = v;
  }
  __syncthreads();
  float4 qreg[16];
#pragma unroll
  for (int i = 0; i < 16; i++) qreg[i] = *(const float4*)&QPs[qrow * 68 + i * 4];

  float l = 0.f;
  float4 o = make_float4(0.f, 0.f, 0.f, 0.f);

  for (int kt = 0; kt < nk; kt += 64) {
    const int nkt = min(64, nk - kt);
    __syncthreads();                      // prior PV reads + qreg reads done
#pragma unroll
    for (int it = 0; it < 4; it++) {
      const int fidx = it * 256 + tid;
      const int row = fidx >> 4, c4 = fidx & 15;
      if (row < nkt) {
        const long src = (long)kl[klo + kt + row] * E_ + c4 * 4;
        *(float4*)&Ks[row * 68 + c4 * 4] = *(const float4*)(Kb + src);
        *(float4*)&Vs[row * 68 + c4 * 4] = *(const float4*)(Vb + src);
      } else {
        *(float4*)&Vs[row * 68 + c4 * 4] = make_float4(0.f, 0.f, 0.f, 0.f);
      }
    }
    __syncthreads();
    // S phase: thread computes 4 scores k = kk*16+col from register Q
#pragma unroll
    for (int kk = 0; kk < 4; kk++) {
      const int k = kk * 16 + col;
      float p = 0.f;
      if (k < nkt) {
        const float* kp = &Ks[k * 68];
        float s = 0.f;
#pragma unroll
        for (int d4 = 0; d4 < 16; d4++) {
          const float4 c = *(const float4*)(kp + d4 * 4);
          s += qreg[d4].x * c.x + qreg[d4].y * c.y +
               qreg[d4].z * c.z + qreg[d4].w * c.w;
        }
        p = __expf(s * 0.125f);           // 1/sqrt(64)
      }
      QPs[qrow * 68 + k] = p;             // P (reuses Q staging buffer)
    }
    __syncthreads();
    // PV phase: unrolled x4, no guards (P=0 and V=0 beyond nkt)
    const int nk4 = (nkt + 3) >> 2;
#pragma unroll 2
    for (int k4 = 0; k4 < nk4; k4++) {
      const float4 pk = *(const float4*)&QPs[qrow * 68 + k4 * 4];
      const float4 v0 = *(const float4*)&Vs[(k4 * 4 + 0) * 68 + col * 4];
      const float4 v1 = *(const float4*)&Vs[(k4 * 4 + 1) * 68 + col * 4];
      const float4 v2 = *(const float4*)&Vs[(k4 * 4 + 2) * 68 + col * 4];
      const float4 v3 = *(const float4*)&Vs[(k4 * 4 + 3) * 68 + col * 4];
      l += (pk.x + pk.y) + (pk.z + pk.w);
      o.x += pk.x * v0.x + pk.y * v1.x + pk.z * v2.x + pk.w * v3.x;
      o.y += pk.x * v0.y + pk.y * v1.y + pk.z * v2.y + pk.w * v3.y;
      o.z += pk.x * v0.z + pk.y * v1.z + pk.z * v2.z + pk.w * v3.z;
      o.w += pk.x * v0.w + pk.y * v1.w + pk.z * v2.w + pk.w * v3.w;
    }
  }

  if (qrow < nqt) {
    // l includes only true keys (P=0 padding); l >= e^{smin} > 0 since nk>0.
    const float inv = 0.5f / l;
    const int t = ql[qlo + qrow];
    float* op = attn + ((long)b * T_ + t) * E_ + h * DH_ + col * 4;
    atomicAdd(op + 0, o.x * inv);
    atomicAdd(op + 1, o.y * inv);
    atomicAdd(op + 2, o.z * inv);
    atomicAdd(op + 3, o.w * inv);
  }
}

// ---------------------------------------------------------------------------
extern "C" void kernel_launch(void* const* d_in, const int* in_sizes, int n_in,
                              void* d_out, int out_size, void* d_ws, size_t ws_size,
                              hipStream_t stream) {
  const float* query = (const float*)d_in[0];
  const float* key   = (const float*)d_in[1];
  const float* value = (const float*)d_in[2];
  const float* Wq = (const float*)d_in[3];
  const float* bq = (const float*)d_in[4];
  const float* Wk = (const float*)d_in[5];
  const float* bk = (const float*)d_in[6];
  const float* Wv = (const float*)d_in[7];
  const float* bv = (const float*)d_in[8];
  const float* Wo = (const float*)d_in[9];
  const float* bo = (const float*)d_in[10];
  const float* lshW = (const float*)d_in[11];
  const float* lshb = (const float*)d_in[12];

  const size_t MSZ = (size_t)M_ * E_;
  float* Q    = (float*)d_ws;            //  8 MB
  float* K    = Q + MSZ;                 //  8 MB
  float* V    = K + MSZ;                 //  8 MB
  float* attn = V + MSZ;                 //  8 MB (atomic round-accumulated)
  int* qh     = (int*)(attn + MSZ);      // [NSEG][T_]
  int* kh     = qh + NSEG * T_;
  int* klist  = kh + NSEG * T_;
  int* qlist  = klist + NSEG * T_;
  int* kcnt   = qlist + NSEG * T_;       // [NSEG][32], start of memset region
  int* qcnt   = kcnt + NSEG * NBUCKET;   // [NSEG][32]
  int* ntasks = qcnt + NSEG * NBUCKET;   // [1], end of memset region
  int* kcur   = ntasks + 1;
  int* qcur   = kcur + NSEG * NBUCKET;
  int* koff   = qcur + NSEG * NBUCKET;   // [NSEG][33]
  int* qoff   = koff + NSEG * (NBUCKET + 1);
  int* tasks  = qoff + NSEG * (NBUCKET + 1);   // [MAXTASK]

  qkv_gemm<<<dim3(E_ / 64, M_ / 64, 3), 256, 0, stream>>>(
      query, key, value, Wq, bq, Wk, bk, Wv, bv, Q, K, V);
  hash_kernel<<<dim3(1024), 128, 0, stream>>>(
      Q, K, lshW, lshb, qh, kh);
  (void)hipMemsetAsync(kcnt, 0, (2 * NSEG * NBUCKET + 1) * sizeof(int), stream);
  (void)hipMemsetAsync(attn, 0, MSZ * sizeof(float), stream);
  hist_kernel<<<dim3(NSEG * T_ / 256), 256, 0, stream>>>(kh, kcnt);
  hist_kernel<<<dim3(NSEG * T_ / 256), 256, 0, stream>>>(qh, qcnt);
  scan_kernel<<<dim3(1), 64, 0, stream>>>(kcnt, koff, kcur, qcnt, qoff, qcur,
                                          ntasks, tasks);
  scatter_kernel<<<dim3(NSEG * T_ / 256), 256, 0, stream>>>(kh, kcur, klist);
  scatter_kernel<<<dim3(NSEG * T_ / 256), 256, 0, stream>>>(qh, qcur, qlist);
  attn_task<<<dim3(MAXTASK), 256, 0, stream>>>(
      Q, K, V, qlist, qoff, klist, koff, tasks, ntasks, attn);
  out_gemm<<<dim3(E_ / 64, M_ / 64, 1), 256, 0, stream>>>(
      attn, Wo, bo, (float*)d_out);
}